// Round 8
// baseline (249.726 us; speedup 1.0000x reference)
//
#include <hip/hip_runtime.h>
#include <math.h>

// Problem constants (match reference setup_inputs)
#define BB 64       // batch
#define KK 4        // classes
#define CC 256      // feature dim
#define NN 8192     // bank entries per class
#define NROWS (KK*NN)        // 32768 bank rows
#define GRID_F 512           // fused WGs (512 thr = 8 waves; 2 waves per 16-row tile)
#define WPG 8                // waves per WG

// d_ws byte offsets
#define WS_B_OFF     0        // 32768 B : bf16 anchor B-fragments (frag order)
#define WS_SLOT_OFF  32768    // 8192 B  : double slots[512][2]
#define WS_NLL_OFF   40960    // 256 B   : float nll[64]
#define WS_INTRA_OFF 41216    // 256 B   : float intra[64]
#define WS_TKT_OFF   41472    // 4 B     : unsigned ticket
#define WS_PROBE_OFF 1048576  // 32 KB   : probe partials (1 float per wave)

#define EPS_NLL 1e-7f

typedef __attribute__((ext_vector_type(8))) short bf16x8;  // MFMA A/B frag
typedef __attribute__((ext_vector_type(4))) float f32x4;   // MFMA C/D frag

__device__ __forceinline__ float4 f4add(float4 a, float4 b){ return make_float4(a.x+b.x, a.y+b.y, a.z+b.z, a.w+b.w); }
__device__ __forceinline__ float4 f4scale(float4 a, float s){ return make_float4(a.x*s, a.y*s, a.z*s, a.w*s); }
__device__ __forceinline__ float dot4(float4 a, float4 b){ return a.x*b.x + a.y*b.y + a.z*b.z + a.w*b.w; }

__device__ __forceinline__ float wred(float v){
#pragma unroll
  for (int m = 32; m >= 1; m >>= 1) v += __shfl_xor(v, m, 64);
  return v;
}

// fp32 -> bf16 round-to-nearest-even (bit trick; no NaN inputs here)
__device__ __forceinline__ unsigned short f2bf(float x){
  union { float f; unsigned u; } v; v.f = x;
  unsigned r = v.u + 0x7fffu + ((v.u >> 16) & 1u);
  return (unsigned short)(r >> 16);
}

// ---------------------------------------------------------------------------
// probe_stream: maximal-MLP full-bank streaming read. 2048 WGs x 256 thr
// (no LDS, tiny VGPR, no barriers): 16 independent grid-strided float4 loads
// per thread, sum, wave-reduce, 1 write/wave. Measures in-situ achievable
// read BW for this buffer; also fully warms L3 (134 MB < 256 MB) for fused.
// ---------------------------------------------------------------------------
#define PS_THREADS (2048*256)
__global__ __launch_bounds__(256) void probe_stream_kernel(
    const float* __restrict__ bank, char* __restrict__ ws)
{
  const int tid = blockIdx.x * 256 + threadIdx.x;
  const float4* b4 = (const float4*)bank;   // 8M float4 total

  float4 a = make_float4(0.f, 0.f, 0.f, 0.f);
#pragma unroll
  for (int j = 0; j < 16; ++j)
    a = f4add(a, b4[(size_t)tid + (size_t)j * PS_THREADS]);

  float r = wred(dot4(a, make_float4(1.f, 1.f, 1.f, 1.f)));
  if ((threadIdx.x & 63) == 0)
    ((float*)(ws + WS_PROBE_OFF))[(blockIdx.x << 2) | (threadIdx.x >> 6)] = r;
}

// ---------------------------------------------------------------------------
// prep: per-b (64 blocks, 1 wave each)  [unchanged, verified r4-r7]
// ---------------------------------------------------------------------------
__global__ __launch_bounds__(64) void prep_kernel(
    const float* __restrict__ hazards, const float* __restrict__ S,
    const float* __restrict__ indiv,   const float* __restrict__ gene,
    const float* __restrict__ path,    const int* __restrict__ label,
    const int* __restrict__ cvec,      char* __restrict__ ws)
{
  const int b = blockIdx.x;
  const int lane = threadIdx.x;          // 0..63, owns k = 4*lane .. 4*lane+3

  const float4* ind4 = (const float4*)indiv + (size_t)b * 256;  // [4][64] float4
  float4 i0 = ind4[  0 + lane];
  float4 i1 = ind4[ 64 + lane];
  float4 i2 = ind4[128 + lane];
  float4 i3 = ind4[192 + lane];
  float4 g  = ((const float4*)gene)[b*64 + lane];
  float4 p  = ((const float4*)path)[b*64 + lane];

  // anchor = l2norm(mean over the 4 components)
  float4 am = f4scale(f4add(f4add(i0, i1), f4add(i2, i3)), 0.25f);
  float na = sqrtf(wred(dot4(am, am)));
  float4 an = f4scale(am, 1.0f / fmaxf(na, 1e-12f));

  // write bf16 B-fragment: this lane covers k = 4*cq..4*cq+3 of anchor b
  {
    const int cq = lane;
    const unsigned addr = (unsigned)((cq >> 3) * 4096          // kc
                        + (b >> 4) * 1024                      // nt
                        + ((((cq >> 1) & 3) * 16) + (b & 15)) * 16  // frag lane
                        + (cq & 1) * 8);                       // half (j>>2)
    ushort4 h4;
    h4.x = f2bf(an.x); h4.y = f2bf(an.y); h4.z = f2bf(an.z); h4.w = f2bf(an.w);
    *(ushort4*)(ws + WS_B_OFF + addr) = h4;
  }

  // l2norm the 6 vectors (4 indiv comps, gene, path)
  float4 v[6] = {i0, i1, i2, i3, g, p};
#pragma unroll
  for (int j = 0; j < 6; ++j) {
    float n = sqrtf(wred(dot4(v[j], v[j])));
    v[j] = f4scale(v[j], 1.0f / fmaxf(n, 1e-12f));
  }

  // sims[p][t] = indiv_n[p] . gp_n[t]
  float s[4][2];
#pragma unroll
  for (int pp = 0; pp < 4; ++pp)
#pragma unroll
    for (int t = 0; t < 2; ++t)
      s[pp][t] = wred(dot4(v[pp], v[4+t]));

  if (lane == 0) {
    // MASK rows (common, synergy, g_spec, p_spec) x (gene, path):
    // [[1,1],[0,0],[1,0],[0,1]]; term = |s|*(1-m) - m*s
    float intra = (-s[0][0]) + (-s[0][1])
                + fabsf(s[1][0]) + fabsf(s[1][1])
                + (-s[2][0]) + fabsf(s[2][1])
                + fabsf(s[3][0]) + (-s[3][1]);
    intra = intra * 0.125f + 1.0f;
    ((float*)(ws + WS_INTRA_OFF))[b] = intra;

    // NLL surv (ALPHA = 0)
    int   Y  = label[b];
    float cf = (float)cvec[b];
    float s_y  = (Y == 0) ? 1.0f : S[b*KK + Y - 1];  // S_padded[Y]
    float s_y1 = S[b*KK + Y];                         // S_padded[Y+1]
    float h_y  = hazards[b*KK + Y];
    float neg_l = -cf * logf(fmaxf(s_y1, EPS_NLL))
                  - (1.0f - cf) * (logf(fmaxf(s_y, EPS_NLL)) + logf(fmaxf(h_y, EPS_NLL)));
    ((float*)(ws + WS_NLL_OFF))[b] = neg_l;
  }
}

// ---------------------------------------------------------------------------
// fused v7 (unchanged from r7): 4096 waves, 2 waves share a 16-row tile,
// depth-2 pipelined staging, XOR-swizzled LDS A-tile, B-frags from global.
// ---------------------------------------------------------------------------
__global__ __launch_bounds__(512, 4) void fused_kernel(
    const float* __restrict__ bank, const int* __restrict__ label,
    char* __restrict__ ws, float* __restrict__ out)
{
  __shared__ uint4 At4[WPG/2][512];         // 32 KB: 4 tiles x (16 rows x 512B)
  __shared__ double redw[WPG][2];
  __shared__ unsigned tkt_s;

  const int tid  = threadIdx.x;
  const int wave = tid >> 6;
  const int lane = tid & 63;
  const int lm   = lane & 15;               // A-row / anchor-in-ntile
  const int lg   = lane >> 4;               // k-group

  const int tileInWG = wave >> 1;
  const int sub      = wave & 1;            // which half: rows + nt quadrants
  const int gtile    = blockIdx.x * (WPG/2) + tileInWG;  // 0..2047
  const int row0     = gtile * 16;
  const int kk       = row0 >> 13;          // class of the whole tile (16|8192)
  char* At = (char*)&At4[tileInWG][0];

  const float4* b4 = (const float4*)bank;   // entry stride 256 float4
  const int rbase = row0 + sub * 8;         // this wave stages rows rbase..rbase+7

  // ---- stage 8 rows: 4 passes x 2 rows, depth-2 software pipeline ----
  float4 rbuf[2][2][4];                     // [buf][row][comp], all-static idx
#pragma unroll
  for (int rr = 0; rr < 2; ++rr)
#pragma unroll
    for (int c = 0; c < 4; ++c)
      rbuf[0][rr][c] = b4[(size_t)(rbase + rr) * 256 + c * 64 + lane];

#pragma unroll
  for (int p = 0; p < 4; ++p) {
    const int cur = p & 1;
    if (p < 3) {
      const int nxt = cur ^ 1;
#pragma unroll
      for (int rr = 0; rr < 2; ++rr)
#pragma unroll
        for (int c = 0; c < 4; ++c)
          rbuf[nxt][rr][c] = b4[(size_t)(rbase + (p+1)*2 + rr) * 256 + c * 64 + lane];
    }
#pragma unroll
    for (int rr = 0; rr < 2; ++rr) {
      // normalized = mean/||mean|| = sum/||sum||
      float4 m = f4add(f4add(rbuf[cur][rr][0], rbuf[cur][rr][1]),
                       f4add(rbuf[cur][rr][2], rbuf[cur][rr][3]));
      float ss = wred(dot4(m, m));
      float rs = rsqrtf(fmaxf(ss, 1e-24f));
      const int lr = sub * 8 + p * 2 + rr;
      ushort4 h4;
      h4.x = f2bf(m.x * rs); h4.y = f2bf(m.y * rs);
      h4.z = f2bf(m.z * rs); h4.w = f2bf(m.w * rs);
      // lane owns k=4*lane..4*lane+3 -> row byte offset lane*8, XOR-swizzled
      *(ushort4*)(At + lr*512 + ((lane*8) ^ ((lr & 7) << 4))) = h4;
    }
  }

  __syncthreads();   // partner wave wrote the other 8 rows of our tile

  // A-frags: lane (lm,lg), frag kc <-> row lm, k = kc*32+lg*8+j (j=0..7)
  bf16x8 af[8];
#pragma unroll
  for (int kc = 0; kc < 8; ++kc)
    af[kc] = *(const bf16x8*)(At + lm*512 + ((kc*64 + lg*16) ^ ((lm & 7) << 4)));

  // ---- MFMA: this wave covers nt = sub*2 + {0,1}; B-frags from global (L2) ----
  const char* Bg = ws + WS_B_OFF;
  const int nt0 = sub * 2;
  int lab0 = label[nt0*16 + lm];
  int lab1 = label[(nt0+1)*16 + lm];

  f32x4 acc0 = {0,0,0,0}, acc1 = {0,0,0,0};
  bf16x8 bfr[2][2];                         // [buf][nt], depth-2 by kc
#pragma unroll
  for (int nt = 0; nt < 2; ++nt)
    bfr[0][nt] = *(const bf16x8*)(Bg + (0*4 + nt0 + nt)*1024 + lane*16);

#pragma unroll
  for (int kc = 0; kc < 8; ++kc) {
    const int cur = kc & 1;
    if (kc < 7) {
      const int nxt = cur ^ 1;
#pragma unroll
      for (int nt = 0; nt < 2; ++nt)
        bfr[nxt][nt] = *(const bf16x8*)(Bg + ((kc+1)*4 + nt0 + nt)*1024 + lane*16);
    }
    acc0 = __builtin_amdgcn_mfma_f32_16x16x32_bf16(af[kc], bfr[cur][0], acc0, 0, 0, 0);
    acc1 = __builtin_amdgcn_mfma_f32_16x16x32_bf16(af[kc], bfr[cur][1], acc1, 0, 0, 0);
  }

  // ---- exp(sim/TAU), classify by anchor label vs tile class ----
  // D layout (verified): col n = lane&15 (anchor), row m = (lane>>4)*4+reg
  float epf = 0.0f, enf = 0.0f;
  {
    float es0 = expf(acc0.x * 0.5f) + expf(acc0.y * 0.5f)
              + expf(acc0.z * 0.5f) + expf(acc0.w * 0.5f);
    if (lab0 == kk) epf += es0; else enf += es0;
    float es1 = expf(acc1.x * 0.5f) + expf(acc1.y * 0.5f)
              + expf(acc1.z * 0.5f) + expf(acc1.w * 0.5f);
    if (lab1 == kk) epf += es1; else enf += es1;
  }

  epf = wred(epf);
  enf = wred(enf);
  if (lane == 0) {
    redw[wave][0] = (double)epf;
    redw[wave][1] = (double)enf;
  }
  __syncthreads();

  double*   slots  = (double*)(ws + WS_SLOT_OFF);
  unsigned* ticket = (unsigned*)(ws + WS_TKT_OFF);

  if (tid == 0) {
    double bep = 0.0, ben = 0.0;
#pragma unroll
    for (int w = 0; w < WPG; ++w) { bep += redw[w][0]; ben += redw[w][1]; }
    slots[blockIdx.x*2 + 0] = bep;
    slots[blockIdx.x*2 + 1] = ben;
    __threadfence();
    tkt_s = atomicAdd(ticket, 1u);
  }
  __syncthreads();

  if (tkt_s == GRID_F - 1 && wave == 0) {   // last WG finalizes
    __threadfence();
    double pep = 0.0, pen = 0.0;
    for (int i = lane; i < GRID_F; i += 64) {
      pep += slots[2*i + 0];
      pen += slots[2*i + 1];
    }
#pragma unroll
    for (int m = 32; m >= 1; m >>= 1) {
      pep += __shfl_xor(pep, m, 64);
      pen += __shfl_xor(pen, m, 64);
    }
    float scal = ((const float*)(ws + WS_NLL_OFF))[lane]
               + ((const float*)(ws + WS_INTRA_OFF))[lane];
    scal = wred(scal);
    if (lane == 0) {
      double ep = pep / (double)(BB * NN);              // mean over positives
      double en = pen / (double)(BB * (KK-1) * NN);     // mean over negatives
      double inter = -log((ep + 1e-8) / (ep + en + 1e-8));
      out[0] = (float)((double)scal / 64.0 + inter);
    }
  }
}

extern "C" void kernel_launch(void* const* d_in, const int* in_sizes, int n_in,
                              void* d_out, int out_size, void* d_ws, size_t ws_size,
                              hipStream_t stream)
{
  const float* hazards = (const float*)d_in[0];
  const float* S       = (const float*)d_in[1];
  const float* indiv   = (const float*)d_in[2];
  const float* gene    = (const float*)d_in[3];
  const float* path    = (const float*)d_in[4];
  const float* bank    = (const float*)d_in[5];
  const int*   label   = (const int*)d_in[6];
  const int*   cvec    = (const int*)d_in[7];
  char*  ws  = (char*)d_ws;
  float* out = (float*)d_out;

  hipMemsetAsync(ws + WS_TKT_OFF, 0, 4, stream);  // zero the ticket only
  probe_stream_kernel<<<dim3(2048), dim3(256), 0, stream>>>(bank, ws);
  prep_kernel<<<dim3(BB), dim3(64), 0, stream>>>(hazards, S, indiv, gene, path, label, cvec, ws);
  fused_kernel<<<dim3(GRID_F), dim3(512), 0, stream>>>(bank, label, ws, out);
}

// Round 10
// 228.403 us; speedup vs baseline: 1.0934x; 1.0934x over previous
//
#include <hip/hip_runtime.h>
#include <math.h>

// Problem constants (match reference setup_inputs)
#define BB 64       // batch
#define KK 4        // classes
#define CC 256      // feature dim
#define NN 8192     // bank entries per class
#define NROWS (KK*NN)        // 32768 bank rows
#define GRID_NORM 4096       // norm_stream WGs (256 thr, 4 waves, 2 rows/wave)
#define GRID_INTER 512       // inter WGs
#define WPG 4                // waves per WG (256 threads)

// d_ws byte offsets
#define WS_BN_OFF    0           // 16777216 B : bf16 normalized rows, A-frag order
                                 //   addr = tile*8192 + kc*1024 + lane*16
#define WS_B_OFF     16777216    // 32768 B : bf16 anchor B-fragments (frag order)
#define WS_SLOT_OFF  16809984    // 8192 B  : double slots[512][2]
#define WS_NLL_OFF   16818176    // 256 B   : float nll[64]
#define WS_INTRA_OFF 16818432    // 256 B   : float intra[64]
#define WS_TKT_OFF   16818688    // 4 B     : unsigned ticket

#define EPS_NLL 1e-7f

typedef __attribute__((ext_vector_type(8))) short bf16x8;  // MFMA A/B frag
typedef __attribute__((ext_vector_type(4))) float f32x4;   // MFMA C/D frag

__device__ __forceinline__ float4 f4add(float4 a, float4 b){ return make_float4(a.x+b.x, a.y+b.y, a.z+b.z, a.w+b.w); }
__device__ __forceinline__ float4 f4scale(float4 a, float s){ return make_float4(a.x*s, a.y*s, a.z*s, a.w*s); }
__device__ __forceinline__ float dot4(float4 a, float4 b){ return a.x*b.x + a.y*b.y + a.z*b.z + a.w*b.w; }

__device__ __forceinline__ float wred(float v){
#pragma unroll
  for (int m = 32; m >= 1; m >>= 1) v += __shfl_xor(v, m, 64);
  return v;
}

// fp32 -> bf16 round-to-nearest-even (bit trick; no NaN inputs here)
__device__ __forceinline__ unsigned short f2bf(float x){
  union { float f; unsigned u; } v; v.f = x;
  unsigned r = v.u + 0x7fffu + ((v.u >> 16) & 1u);
  return (unsigned short)(r >> 16);
}

// ---------------------------------------------------------------------------
// prep: per-b (64 blocks, 1 wave each)  [unchanged, verified r4-r8]
// ---------------------------------------------------------------------------
__global__ __launch_bounds__(64) void prep_kernel(
    const float* __restrict__ hazards, const float* __restrict__ S,
    const float* __restrict__ indiv,   const float* __restrict__ gene,
    const float* __restrict__ path,    const int* __restrict__ label,
    const int* __restrict__ cvec,      char* __restrict__ ws)
{
  const int b = blockIdx.x;
  const int lane = threadIdx.x;          // 0..63, owns k = 4*lane .. 4*lane+3

  const float4* ind4 = (const float4*)indiv + (size_t)b * 256;  // [4][64] float4
  float4 i0 = ind4[  0 + lane];
  float4 i1 = ind4[ 64 + lane];
  float4 i2 = ind4[128 + lane];
  float4 i3 = ind4[192 + lane];
  float4 g  = ((const float4*)gene)[b*64 + lane];
  float4 p  = ((const float4*)path)[b*64 + lane];

  // anchor = l2norm(mean over the 4 components)
  float4 am = f4scale(f4add(f4add(i0, i1), f4add(i2, i3)), 0.25f);
  float na = sqrtf(wred(dot4(am, am)));
  float4 an = f4scale(am, 1.0f / fmaxf(na, 1e-12f));

  // write bf16 B-fragment: this lane covers k = 4*cq..4*cq+3 of anchor b
  {
    const int cq = lane;
    const unsigned addr = (unsigned)((cq >> 3) * 4096          // kc
                        + (b >> 4) * 1024                      // nt
                        + ((((cq >> 1) & 3) * 16) + (b & 15)) * 16  // frag lane
                        + (cq & 1) * 8);                       // half (j>>2)
    ushort4 h4;
    h4.x = f2bf(an.x); h4.y = f2bf(an.y); h4.z = f2bf(an.z); h4.w = f2bf(an.w);
    *(ushort4*)(ws + WS_B_OFF + addr) = h4;
  }

  // l2norm the 6 vectors (4 indiv comps, gene, path)
  float4 v[6] = {i0, i1, i2, i3, g, p};
#pragma unroll
  for (int j = 0; j < 6; ++j) {
    float n = sqrtf(wred(dot4(v[j], v[j])));
    v[j] = f4scale(v[j], 1.0f / fmaxf(n, 1e-12f));
  }

  // sims[p][t] = indiv_n[p] . gp_n[t]
  float s[4][2];
#pragma unroll
  for (int pp = 0; pp < 4; ++pp)
#pragma unroll
    for (int t = 0; t < 2; ++t)
      s[pp][t] = wred(dot4(v[pp], v[4+t]));

  if (lane == 0) {
    // MASK rows (common, synergy, g_spec, p_spec) x (gene, path):
    // [[1,1],[0,0],[1,0],[0,1]]; term = |s|*(1-m) - m*s
    float intra = (-s[0][0]) + (-s[0][1])
                + fabsf(s[1][0]) + fabsf(s[1][1])
                + (-s[2][0]) + fabsf(s[2][1])
                + fabsf(s[3][0]) + (-s[3][1]);
    intra = intra * 0.125f + 1.0f;
    ((float*)(ws + WS_INTRA_OFF))[b] = intra;

    // NLL surv (ALPHA = 0)
    int   Y  = label[b];
    float cf = (float)cvec[b];
    float s_y  = (Y == 0) ? 1.0f : S[b*KK + Y - 1];  // S_padded[Y]
    float s_y1 = S[b*KK + Y];                         // S_padded[Y+1]
    float h_y  = hazards[b*KK + Y];
    float neg_l = -cf * logf(fmaxf(s_y1, EPS_NLL))
                  - (1.0f - cf) * (logf(fmaxf(s_y, EPS_NLL)) + logf(fmaxf(h_y, EPS_NLL)));
    ((float*)(ws + WS_NLL_OFF))[b] = neg_l;
  }
}

// ---------------------------------------------------------------------------
// norm_stream v9: probe-shaped bank pass. 4096 WGs x 256 thr (32 waves/CU via
// launch_bounds(256,8)); each wave owns 2 rows: 8 independent coalesced 1KB
// loads, ONE drain, 2 ILP-interleaved shuffle-reduce chains, rsqrt, and
// frag-ordered bf16 stores (8B/lane/row).
//   output addr: tile*8192 + kc*1024 + (lm + 16*lg)*16 + half*8
//   (lane l holds k=4l..4l+3: kc=l>>3, lg=(l>>1)&3, half=l&1)
// ---------------------------------------------------------------------------
__global__ __launch_bounds__(256, 8) void norm_stream_kernel(
    const float* __restrict__ bank, char* __restrict__ ws)
{
  const int tid  = threadIdx.x;
  const int wave = tid >> 6;
  const int lane = tid & 63;
  const int gw   = blockIdx.x * WPG + wave;   // 0..16383
  const int row0 = gw * 2;

  const float4* b4 = (const float4*)bank;     // entry stride 256 float4

  // 8 independent coalesced 1KB loads (2 rows x 4 comps)
  float4 r0[4], r1[4];
#pragma unroll
  for (int c = 0; c < 4; ++c) r0[c] = b4[(size_t)row0       * 256 + c * 64 + lane];
#pragma unroll
  for (int c = 0; c < 4; ++c) r1[c] = b4[(size_t)(row0 + 1) * 256 + c * 64 + lane];

  // normalized = mean/||mean|| = sum/||sum||
  float4 m0 = f4add(f4add(r0[0], r0[1]), f4add(r0[2], r0[3]));
  float4 m1 = f4add(f4add(r1[0], r1[1]), f4add(r1[2], r1[3]));
  float s0 = dot4(m0, m0);
  float s1 = dot4(m1, m1);
  // two independent butterfly chains, interleaved for ILP
#pragma unroll
  for (int sh = 32; sh >= 1; sh >>= 1) {
    s0 += __shfl_xor(s0, sh, 64);
    s1 += __shfl_xor(s1, sh, 64);
  }
  const float q0 = rsqrtf(fmaxf(s0, 1e-24f));
  const float q1 = rsqrtf(fmaxf(s1, 1e-24f));

  // frag-ordered destinations
  const unsigned lanedest = (unsigned)((lane >> 3) * 1024      // kc
                          + ((lane >> 1) & 3) * 256            // lg
                          + (lane & 1) * 8);                   // half
  const int t0 = row0 >> 4,        lm0 = row0 & 15;
  const int t1 = (row0 + 1) >> 4,  lm1 = (row0 + 1) & 15;

  ushort4 h0, h1;
  h0.x = f2bf(m0.x * q0); h0.y = f2bf(m0.y * q0);
  h0.z = f2bf(m0.z * q0); h0.w = f2bf(m0.w * q0);
  h1.x = f2bf(m1.x * q1); h1.y = f2bf(m1.y * q1);
  h1.z = f2bf(m1.z * q1); h1.w = f2bf(m1.w * q1);
  *(ushort4*)(ws + WS_BN_OFF + (size_t)t0 * 8192 + lanedest + lm0 * 16) = h0;
  *(ushort4*)(ws + WS_BN_OFF + (size_t)t1 * 8192 + lanedest + lm1 * 16) = h1;
}

// ---------------------------------------------------------------------------
// inter v9: each wave owns one 16-row tile; A-frags are 8 CONTIGUOUS coalesced
// 1KB loads from the frag-ordered bn buffer (L2/L3-hot). B-frags staged in
// 32KB LDS. 8x4 mfma_f32_16x16x32_bf16, exp, ticket-reduce.
// D layout (verified): col n = lane&15, row m = (lane>>4)*4+reg.
// ---------------------------------------------------------------------------
__global__ __launch_bounds__(256) void inter_kernel(
    const int* __restrict__ label, char* __restrict__ ws, float* __restrict__ out)
{
  __shared__ uint4 Bl[2048];                // 32 KB: 32 frags x 64 lanes x 16B
  __shared__ double redw[WPG][2];
  __shared__ unsigned tkt_s;

  const int tid  = threadIdx.x;
  const int wave = tid >> 6;
  const int lane = tid & 63;
  const int lm   = lane & 15;               // anchor-in-ntile for labels

  // stage B-fragments into LDS (tid-contiguous uint4 loads)
  const uint4* Bg = (const uint4*)(ws + WS_B_OFF);
#pragma unroll
  for (int i = 0; i < 8; ++i) Bl[tid + i*256] = Bg[tid + i*256];
  __syncthreads();

  const int gw   = blockIdx.x * WPG + wave;  // tile id, 0..2047
  const int kk   = (gw * 16) >> 13;          // class of the whole tile (16|8192)

  int lab[4];
#pragma unroll
  for (int nt = 0; nt < 4; ++nt) lab[nt] = label[nt*16 + lm];

  // ---- A-frags: 8 independent CONTIGUOUS 1KB loads ----
  const char* bnp = ws + WS_BN_OFF + (size_t)gw * 8192;
  bf16x8 af[8];
#pragma unroll
  for (int kc = 0; kc < 8; ++kc)
    af[kc] = *(const bf16x8*)(bnp + kc * 1024 + lane * 16);

  // ---- MFMA: A-frags x B-frags ----
  f32x4 acc0 = {0,0,0,0}, acc1 = {0,0,0,0}, acc2 = {0,0,0,0}, acc3 = {0,0,0,0};
#pragma unroll
  for (int kc = 0; kc < 8; ++kc) {
    acc0 = __builtin_amdgcn_mfma_f32_16x16x32_bf16(af[kc], *(const bf16x8*)&Bl[(kc*4+0)*64 + lane], acc0, 0, 0, 0);
    acc1 = __builtin_amdgcn_mfma_f32_16x16x32_bf16(af[kc], *(const bf16x8*)&Bl[(kc*4+1)*64 + lane], acc1, 0, 0, 0);
    acc2 = __builtin_amdgcn_mfma_f32_16x16x32_bf16(af[kc], *(const bf16x8*)&Bl[(kc*4+2)*64 + lane], acc2, 0, 0, 0);
    acc3 = __builtin_amdgcn_mfma_f32_16x16x32_bf16(af[kc], *(const bf16x8*)&Bl[(kc*4+3)*64 + lane], acc3, 0, 0, 0);
  }

  // ---- exp(sim/TAU), classify by anchor label vs tile class ----
  float epf = 0.0f, enf = 0.0f;
#define DO_NT(ACC, NT)                                                        \
  {                                                                           \
    float es = expf(ACC.x * 0.5f) + expf(ACC.y * 0.5f)                        \
             + expf(ACC.z * 0.5f) + expf(ACC.w * 0.5f);                       \
    if (lab[NT] == kk) epf += es; else enf += es;                             \
  }
  DO_NT(acc0, 0) DO_NT(acc1, 1) DO_NT(acc2, 2) DO_NT(acc3, 3)
#undef DO_NT

  epf = wred(epf);
  enf = wred(enf);
  if (lane == 0) {
    redw[wave][0] = (double)epf;
    redw[wave][1] = (double)enf;
  }
  __syncthreads();

  double*   slots  = (double*)(ws + WS_SLOT_OFF);
  unsigned* ticket = (unsigned*)(ws + WS_TKT_OFF);

  if (tid == 0) {
    double bep = 0.0, ben = 0.0;
#pragma unroll
    for (int w = 0; w < WPG; ++w) { bep += redw[w][0]; ben += redw[w][1]; }
    slots[blockIdx.x*2 + 0] = bep;
    slots[blockIdx.x*2 + 1] = ben;
    __threadfence();
    tkt_s = atomicAdd(ticket, 1u);
  }
  __syncthreads();

  if (tkt_s == GRID_INTER - 1 && wave == 0) {   // last WG finalizes
    __threadfence();
    double pep = 0.0, pen = 0.0;
    for (int i = lane; i < GRID_INTER; i += 64) {
      pep += slots[2*i + 0];
      pen += slots[2*i + 1];
    }
#pragma unroll
    for (int m = 32; m >= 1; m >>= 1) {
      pep += __shfl_xor(pep, m, 64);
      pen += __shfl_xor(pen, m, 64);
    }
    float scal = ((const float*)(ws + WS_NLL_OFF))[lane]
               + ((const float*)(ws + WS_INTRA_OFF))[lane];
    scal = wred(scal);
    if (lane == 0) {
      double ep = pep / (double)(BB * NN);              // mean over positives
      double en = pen / (double)(BB * (KK-1) * NN);     // mean over negatives
      double inter = -log((ep + 1e-8) / (ep + en + 1e-8));
      out[0] = (float)((double)scal / 64.0 + inter);
    }
  }
}

extern "C" void kernel_launch(void* const* d_in, const int* in_sizes, int n_in,
                              void* d_out, int out_size, void* d_ws, size_t ws_size,
                              hipStream_t stream)
{
  const float* hazards = (const float*)d_in[0];
  const float* S       = (const float*)d_in[1];
  const float* indiv   = (const float*)d_in[2];
  const float* gene    = (const float*)d_in[3];
  const float* path    = (const float*)d_in[4];
  const float* bank    = (const float*)d_in[5];
  const int*   label   = (const int*)d_in[6];
  const int*   cvec    = (const int*)d_in[7];
  char*  ws  = (char*)d_ws;
  float* out = (float*)d_out;

  hipMemsetAsync(ws + WS_TKT_OFF, 0, 4, stream);  // zero the ticket only
  prep_kernel<<<dim3(BB), dim3(64), 0, stream>>>(hazards, S, indiv, gene, path, label, cvec, ws);
  norm_stream_kernel<<<dim3(GRID_NORM), dim3(256), 0, stream>>>(bank, ws);
  inter_kernel<<<dim3(GRID_INTER), dim3(256), 0, stream>>>(label, ws, out);
}